// Round 5
// baseline (539.035 us; speedup 1.0000x reference)
//
#include <hip/hip_runtime.h>
#include <hip/hip_bf16.h>

// FastUpConvolution on MI355X — round 5: footprint-staged X + direct-W GEMM.
// The 4 convs (3x3, 2x3, 3x2, 2x2 with matching pads) are one implicit GEMM
//   C[nout=4*256][m=16*32*32] = W[nout][K=9*512] * X[m][K]^T
// over NHWC-padded x with zero-padded taps, computed in bf16 MFMA.
//
// R4 post-mortem: gemm was L2-miss-traffic bound (FETCH 578 MB = 20x inputs,
// 2.4 GB logical reads; WRITE 134 MB = 2x output from half-dense scatter).
// R5: (a) X footprint (6x34 sites) staged to LDS once per 128-ci chunk and
// reused across all 9 taps (X logical reads /5.5, barriers 144 -> 8/block);
// (b) W read straight from global into A-fragments (L2-resident per XCD),
// waves tile n so W reads are minimal — K-loop is MFMA<->VMEM interleaved
// with no barriers (AITER-style); (c) W_t rows interleaved (row = co*4+q) so
// each thread holds all 4 pixel-shuffle quadrants of one (co,h,w) -> dense
// float2 writes (WRITE /2) and fused BN-stats atomics (bn_stats pass gone).
//
// ws layout (28.4 MiB):
//   x_t   : bf16 [16][34][34][512]  @ 0          (18,939,904 B)
//   W_t   : bf16 [1024 rows][9*512] @ 18,939,904 ( 9,437,184 B)  row=co*4+q
//   bias  : f32  [1024]             @ 28,377,088 (     4,096 B)  row=co*4+q
//   stats : f32  [512] sum|sumsq    @ 28,381,184 (     2,048 B)

typedef unsigned short ushort_t;
typedef __attribute__((ext_vector_type(8))) short short8;
typedef __attribute__((ext_vector_type(4))) float floatx4;
typedef __attribute__((ext_vector_type(2))) float floatx2;
typedef __attribute__((ext_vector_type(4))) unsigned short u16x4;
typedef __attribute__((ext_vector_type(8))) unsigned short u16x8;
typedef __attribute__((ext_vector_type(4))) unsigned int u32x4;

#define XT_OFF    0u
#define WT_OFF    18939904u
#define BIAS_OFF  28377088u
#define STATS_OFF 28381184u

// X LDS: 204 sites (6 rows x 34 cols) x (128 ci = 256 B) + 16 B pad = 272 B.
// Site stride 272 B = 68 dwords = 4 banks mod 32 -> b128 reads are 2-way
// (free, m136); staging ds_writes likewise.
#define SSTRIDE 272
#define NSITES  204

__device__ __forceinline__ ushort_t f2bf(float f) {
  unsigned int u = __builtin_bit_cast(unsigned int, f);
  u += 0x7fffu + ((u >> 16) & 1u);   // RNE (values finite here)
  return (ushort_t)(u >> 16);
}

// ---------------------------------------------------------------- prep_x ---
// x[16][512][32][32] (f32) -> x_t[16][34][34][512] bf16, zero-padded NHWC.
// One block per (n, hp). LDS transpose, 128 ci x 32 w per pass.
__global__ __launch_bounds__(256) void prep_x(const float* __restrict__ x,
                                              ushort_t* __restrict__ xt) {
  const int b = blockIdx.x;
  const int n = b / 34, hp = b % 34;
  const int t = threadIdx.x;
  ushort_t* dst = xt + (size_t)(n * 34 + hp) * (34 * 512);
  if (hp == 0 || hp == 33) {              // top/bottom pad rows: zero slice
    u32x4 z = {0u, 0u, 0u, 0u};
    for (int i = t; i < 2176; i += 256) ((u32x4*)dst)[i] = z;
    return;
  }
  const int h = hp - 1;
  {                                        // left/right pad columns
    u32x4 z = {0u, 0u, 0u, 0u};
    if (t < 64) ((u32x4*)dst)[t] = z;
    else if (t < 128) ((u32x4*)(dst + 33 * 512))[t - 64] = z;
  }
  __shared__ ushort_t lds[128 * 36];       // stride 36: 8B align, non-2^k
  const size_t base = (size_t)n * 524288 + (size_t)h * 32;
  for (int ci0 = 0; ci0 < 512; ci0 += 128) {
    __syncthreads();
    {  // load: coalesced along w (f32x4 -> bf16x4)
      const int cil = t >> 3;
      const int w4 = (t & 7) << 2;
#pragma unroll
      for (int cc = 0; cc < 4; ++cc) {
        const int ci = cil + cc * 32;
        floatx4 v = *(const floatx4*)(x + base + (size_t)(ci0 + ci) * 1024 + w4);
        u16x4 hv;
#pragma unroll
        for (int j = 0; j < 4; ++j) hv[j] = f2bf(v[j]);
        *(u16x4*)&lds[ci * 36 + w4] = hv;
      }
    }
    __syncthreads();
    {  // store: 16B contiguous along ci
      const int w = t & 31;
      const int j8 = t >> 5;
#pragma unroll
      for (int cc2 = 0; cc2 < 2; ++cc2) {
        const int cil = cc2 * 64 + j8 * 8;
        u16x8 v;
#pragma unroll
        for (int j = 0; j < 8; ++j) v[j] = lds[(cil + j) * 36 + w];
        *(u16x8*)(dst + (w + 1) * 512 + ci0 + cil) = v;
      }
    }
  }
}

// ---------------------------------------------------------------- prep_w ---
// W_t[row=co*4+q][tap][ci] bf16, tap=dh*3+dw; absent taps -> 0.
// q0=o1(3x3) q1=o2(2x3) q2=o3(3x2) q3=o4(2x2). bias[row] (f32).
__global__ __launch_bounds__(256) void prep_w(
    const float* __restrict__ w1, const float* __restrict__ w2,
    const float* __restrict__ w3, const float* __restrict__ w4,
    const float* __restrict__ b1, const float* __restrict__ b2,
    const float* __restrict__ b3, const float* __restrict__ b4,
    ushort_t* __restrict__ wt, float* __restrict__ bias) {
  const int nout = blockIdx.x;
  const int q = nout >> 8, co = nout & 255;
  const int row = co * 4 + q;
  const int t = threadIdx.x;
  const float* wsrc; const float* bsrc; int khl, kwl;
  if (q == 0)      { wsrc = w1; bsrc = b1; khl = 3; kwl = 3; }
  else if (q == 1) { wsrc = w2; bsrc = b2; khl = 2; kwl = 3; }
  else if (q == 2) { wsrc = w3; bsrc = b3; khl = 3; kwl = 2; }
  else             { wsrc = w4; bsrc = b4; khl = 2; kwl = 2; }
  if (t == 0) bias[row] = bsrc[co];
  ushort_t* dst = wt + (size_t)row * 4608;
  for (int tap = 0; tap < 9; ++tap) {
    const int dh = tap / 3, dw = tap % 3;
    const bool valid = (dh < khl) && (dw < kwl);
#pragma unroll
    for (int cc = 0; cc < 2; ++cc) {
      const int ci = cc * 256 + t;
      ushort_t v = 0;
      if (valid) v = f2bf(wsrc[(((size_t)co * 512 + ci) * khl + dh) * kwl + dw]);
      dst[tap * 512 + ci] = v;
    }
  }
}

// -------------------------------------------------------------- zero_stats --
__global__ void zero_stats(float* __restrict__ stats) {
  stats[threadIdx.x] = 0.f;   // 512 threads
}

// ------------------------------------------------------------------ gemm ---
// Block: 128 m (4h x 32w) x 128 n. 4 waves tile n (32 each), share m + LDS X.
// Per 128-ci chunk: stage X footprint (204 sites x 256 B) once, then loop
// 9 taps x 4 k-steps reading W A-frags direct from global (L2-resident) and
// X B-frags from LDS. Epilogue: +bias, dense 2x2 pixel-shuffle writes, fused
// BN partial sums via atomics.
__global__ __launch_bounds__(256, 2) void gemm_kernel(
    const ushort_t* __restrict__ xt, const ushort_t* __restrict__ wt,
    const float* __restrict__ bias, float* __restrict__ out,
    float* __restrict__ stats) {
  __shared__ char ldsX[NSITES * SSTRIDE];   // 55,488 B
  const int tid = threadIdx.x;
  const int bx = blockIdx.x;
  const int bn = bx & 7, bm = bx >> 3;
  const int m0 = bm << 7;
  const int n0 = bn << 7;
  const int n_img = bm >> 3;            // 8 m-blocks per image
  const int h0 = (bm & 7) << 2;         // x_t padded rows h0..h0+5
  const int wc = tid >> 6, lane = tid & 63;
  const int ri = lane & 15, kg = lane >> 4;
  const int nw0 = n0 + (wc << 5);       // this wave's 32 W_t rows

  // Per-lane W global pointers (A-fragments), fi in {0,1}.
  const char* pW[2];
#pragma unroll
  for (int fi = 0; fi < 2; ++fi)
    pW[fi] = (const char*)wt + (size_t)(nw0 + fi * 16 + ri) * 9216 + (kg << 4);

  // Per-fj X LDS byte base: site = (fj>>1)*34 + (fj&1)*16 + colL (colL = ri).
  int xoff[8];
#pragma unroll
  for (int fj = 0; fj < 8; ++fj)
    xoff[fj] = (((fj >> 1) * 34) + ((fj & 1) << 4) + ri) * SSTRIDE + (kg << 4);

  floatx4 acc[2][8] = {};

  const ushort_t* xrow = xt + (size_t)(n_img * 34 + h0) * (34 * 512);

  for (int chunk = 0; chunk < 4; ++chunk) {
    const int cb = chunk << 8;          // byte offset into a site's 1024 B
    __syncthreads();                    // previous chunk's LDS reads done
    // ---- stage X footprint chunk: 204 sites x 256 B = 52 KB ----
    for (int p = 0; p < 13; ++p) {
      const int idx = p * 256 + tid;
      if (idx < NSITES * 16) {
        const int site = idx >> 4, c16 = idx & 15;
        const int r = site / 34, c = site - r * 34;
        u32x4 v = *(const u32x4*)((const char*)(xrow + (size_t)(r * 34 + c) * 512)
                                  + cb + (c16 << 4));
        *(u32x4*)(ldsX + site * SSTRIDE + (c16 << 4)) = v;
      }
    }
    __syncthreads();
    // ---- 9 taps x 4 k-steps, W direct from global, X from LDS ----
#pragma unroll
    for (int tap = 0; tap < 9; ++tap) {
      const int dh = tap / 3, dw = tap % 3;
      const int tapo = (dh * 34 + dw) * SSTRIDE;
      const int wgo = (tap << 10) + (chunk << 8);
#pragma unroll
      for (int ks = 0; ks < 4; ++ks) {
        short8 a4[2];
#pragma unroll
        for (int fi = 0; fi < 2; ++fi)
          a4[fi] = __builtin_bit_cast(short8,
                     *(const u32x4*)(pW[fi] + wgo + (ks << 6)));
        short8 b4;
#pragma unroll
        for (int fj = 0; fj < 8; ++fj) {
          b4 = *(const short8*)(ldsX + xoff[fj] + tapo + (ks << 6));
          acc[0][fj] = __builtin_amdgcn_mfma_f32_16x16x32_bf16(
              a4[0], b4, acc[0][fj], 0, 0, 0);
          acc[1][fj] = __builtin_amdgcn_mfma_f32_16x16x32_bf16(
              a4[1], b4, acc[1][fj], 0, 0, 0);
        }
      }
    }
  }

  // ---- epilogue: +bias, dense pixel-shuffle writes, fused BN partials ----
  // D layout: col = lane&15 (m), row = quad*4+reg (n); reg = q (quadrant),
  // co = (nw0>>2) + fi*4 + quad. q->(ph,pw): 0->(0,0) 1->(1,0) 2->(0,1)
  // 3->(1,1)  => row h'=2h: (q0,q2), row h'=2h+1: (q1,q3).
  const int colL = ri, quad = kg;
#pragma unroll
  for (int fi = 0; fi < 2; ++fi) {
    const int co = (nw0 >> 2) + fi * 4 + quad;
    const floatx4 bv = *(const floatx4*)(bias + nw0 + fi * 16 + (quad << 2));
    float s = 0.f, s2 = 0.f;
    float* obase = out + ((size_t)(n_img * 256 + co) << 12);
#pragma unroll
    for (int fj = 0; fj < 8; ++fj) {
      const int mg = m0 + (fj << 4) + colL;
      const int hh = (mg >> 5) & 31, ww = mg & 31;
      float v0 = acc[fi][fj][0] + bv[0];
      float v1 = acc[fi][fj][1] + bv[1];
      float v2 = acc[fi][fj][2] + bv[2];
      float v3 = acc[fi][fj][3] + bv[3];
      s += (v0 + v1) + (v2 + v3);
      s2 += v0 * v0 + v1 * v1 + v2 * v2 + v3 * v3;
      float* p = obase + (hh << 7) + (ww << 1);  // (2h)*64 + 2w
      floatx2 e = {v0, v2};
      floatx2 o = {v1, v3};
      *(floatx2*)p = e;
      *(floatx2*)(p + 64) = o;
    }
    // reduce over the 16 colL lanes (quad constant within each 16-lane group)
#pragma unroll
    for (int off = 1; off < 16; off <<= 1) {
      s += __shfl_xor(s, off);
      s2 += __shfl_xor(s2, off);
    }
    if (colL == 0) {
      atomicAdd(&stats[co], s);
      atomicAdd(&stats[256 + co], s2);
    }
  }
}

// -------------------------------------------------------------- bn_apply ---
// In-place f32: y = relu((y-mean)*rstd*gamma + beta), mean/rstd from the
// fused sums. Block per (n, co).
__global__ __launch_bounds__(256) void bn_apply(
    float* __restrict__ y, const float* __restrict__ stats,
    const float* __restrict__ gamma, const float* __restrict__ beta) {
  const int b = blockIdx.x;
  const int co = b & 255;
  const int t = threadIdx.x;
  const float mean = stats[co] * (1.f / 65536.f);
  const float var = stats[256 + co] * (1.f / 65536.f) - mean * mean;
  const float rstd = rsqrtf(var + 1e-5f);
  const float scale = rstd * gamma[co];
  const float shift = beta[co] - mean * scale;
  float* p = y + (size_t)b * 4096;
#pragma unroll
  for (int it = 0; it < 4; ++it) {
    floatx4* q = (floatx4*)(p + (it * 256 + t) * 4);
    floatx4 v = *q;
#pragma unroll
    for (int e = 0; e < 4; ++e) v[e] = fmaxf(v[e] * scale + shift, 0.f);
    *q = v;
  }
}

// ---------------------------------------------------------------- launch ---
extern "C" void kernel_launch(void* const* d_in, const int* in_sizes, int n_in,
                              void* d_out, int out_size, void* d_ws,
                              size_t ws_size, hipStream_t stream) {
  const float* x  = (const float*)d_in[0];
  const float* w1 = (const float*)d_in[1];
  const float* b1 = (const float*)d_in[2];
  const float* w2 = (const float*)d_in[3];
  const float* b2 = (const float*)d_in[4];
  const float* w3 = (const float*)d_in[5];
  const float* b3 = (const float*)d_in[6];
  const float* w4 = (const float*)d_in[7];
  const float* b4 = (const float*)d_in[8];
  const float* gamma = (const float*)d_in[9];
  const float* beta  = (const float*)d_in[10];
  float* out = (float*)d_out;

  char* ws = (char*)d_ws;
  ushort_t* xt   = (ushort_t*)(ws + XT_OFF);
  ushort_t* wt   = (ushort_t*)(ws + WT_OFF);
  float*    bias = (float*)(ws + BIAS_OFF);
  float*    st   = (float*)(ws + STATS_OFF);

  zero_stats<<<1, 512, 0, stream>>>(st);
  prep_x<<<16 * 34, 256, 0, stream>>>(x, xt);
  prep_w<<<1024, 256, 0, stream>>>(w1, w2, w3, w4, b1, b2, b3, b4, wt, bias);
  gemm_kernel<<<1024, 256, 0, stream>>>(xt, wt, bias, out, st);
  bn_apply<<<4096, 256, 0, stream>>>(out, st, gamma, beta);
}

// Round 6
// 380.444 us; speedup vs baseline: 1.4169x; 1.4169x over previous
//
#include <hip/hip_runtime.h>
#include <hip/hip_bf16.h>

// FastUpConvolution on MI355X — round 6: X-footprint LDS reuse + R4 staging.
// One implicit GEMM C[1024][16384] = W[1024][4608] * X[16384][4608]^T over
// NHWC-padded x (zero-padded taps), bf16 MFMA, f32 I/O.
//
// R5 post-mortem: direct-from-global W A-frags -> 1.2 GB logical W traffic +
// spill-signature (FETCH&WRITE both +700 MB, MfmaUtil 15%) -> 417 us. R6
// reverts to R4's reg->LDS staging discipline everywhere, keeps R5's X
// footprint reuse (stage 6x34 sites once per 64-ci chunk, reuse across all
// 9 taps: X logical /5.5) and R5's interleaved-row epilogue (dense 2x2
// writes + fused BN stats). W tile preloaded to regs one tap ahead so L2
// latency overlaps MFMA.
//
// ws layout:
//   x_t   : bf16 [16][34][34][512]  @ 0          (18,939,904 B)
//   W_t   : bf16 [1024 rows][9*512] @ 18,939,904 ( 9,437,184 B)  row=co*4+q
//   bias  : f32  [1024]             @ 28,377,088 (     4,096 B)  row=co*4+q
//   stats : f32  [512] sum|sumsq    @ 28,381,184 (     2,048 B)

typedef unsigned short ushort_t;
typedef __attribute__((ext_vector_type(8))) short short8;
typedef __attribute__((ext_vector_type(4))) float floatx4;
typedef __attribute__((ext_vector_type(2))) float floatx2;
typedef __attribute__((ext_vector_type(4))) unsigned short u16x4;
typedef __attribute__((ext_vector_type(8))) unsigned short u16x8;
typedef __attribute__((ext_vector_type(4))) unsigned int u32x4;

#define XT_OFF    0u
#define WT_OFF    18939904u
#define BIAS_OFF  28377088u
#define STATS_OFF 28381184u

// LDS strides: one 64-ci chunk of a site/row = 128 B data + 8 B pad = 136 B.
// 136 B = 34 dwords ≡ 2 (mod 32) -> 16-lane ri-strided b128 reads hit 16
// distinct even banks, 2-way across kg quarters = free (m136).
#define XSTR 136
#define NSITES 204            // 6 rows x 34 cols footprint

__device__ __forceinline__ ushort_t f2bf(float f) {
  unsigned int u = __builtin_bit_cast(unsigned int, f);
  u += 0x7fffu + ((u >> 16) & 1u);   // RNE (values finite here)
  return (ushort_t)(u >> 16);
}

// ---------------------------------------------------------------- prep_x ---
// x[16][512][32][32] (f32) -> x_t[16][34][34][512] bf16, zero-padded NHWC.
__global__ __launch_bounds__(256) void prep_x(const float* __restrict__ x,
                                              ushort_t* __restrict__ xt) {
  const int b = blockIdx.x;
  const int n = b / 34, hp = b % 34;
  const int t = threadIdx.x;
  ushort_t* dst = xt + (size_t)(n * 34 + hp) * (34 * 512);
  if (hp == 0 || hp == 33) {
    u32x4 z = {0u, 0u, 0u, 0u};
    for (int i = t; i < 2176; i += 256) ((u32x4*)dst)[i] = z;
    return;
  }
  const int h = hp - 1;
  {
    u32x4 z = {0u, 0u, 0u, 0u};
    if (t < 64) ((u32x4*)dst)[t] = z;
    else if (t < 128) ((u32x4*)(dst + 33 * 512))[t - 64] = z;
  }
  __shared__ ushort_t lds[128 * 36];
  const size_t base = (size_t)n * 524288 + (size_t)h * 32;
  for (int ci0 = 0; ci0 < 512; ci0 += 128) {
    __syncthreads();
    {
      const int cil = t >> 3;
      const int w4 = (t & 7) << 2;
#pragma unroll
      for (int cc = 0; cc < 4; ++cc) {
        const int ci = cil + cc * 32;
        floatx4 v = *(const floatx4*)(x + base + (size_t)(ci0 + ci) * 1024 + w4);
        u16x4 hv;
#pragma unroll
        for (int j = 0; j < 4; ++j) hv[j] = f2bf(v[j]);
        *(u16x4*)&lds[ci * 36 + w4] = hv;
      }
    }
    __syncthreads();
    {
      const int w = t & 31;
      const int j8 = t >> 5;
#pragma unroll
      for (int cc2 = 0; cc2 < 2; ++cc2) {
        const int cil = cc2 * 64 + j8 * 8;
        u16x8 v;
#pragma unroll
        for (int j = 0; j < 8; ++j) v[j] = lds[(cil + j) * 36 + w];
        *(u16x8*)(dst + (w + 1) * 512 + ci0 + cil) = v;
      }
    }
  }
}

// ---------------------------------------------------------------- prep_w ---
// W_t[row=co*4+q][tap][ci] bf16; q0=3x3 q1=2x3 q2=3x2 q3=2x2; bias[row].
__global__ __launch_bounds__(256) void prep_w(
    const float* __restrict__ w1, const float* __restrict__ w2,
    const float* __restrict__ w3, const float* __restrict__ w4,
    const float* __restrict__ b1, const float* __restrict__ b2,
    const float* __restrict__ b3, const float* __restrict__ b4,
    ushort_t* __restrict__ wt, float* __restrict__ bias) {
  const int nout = blockIdx.x;
  const int q = nout >> 8, co = nout & 255;
  const int row = co * 4 + q;
  const int t = threadIdx.x;
  const float* wsrc; const float* bsrc; int khl, kwl;
  if (q == 0)      { wsrc = w1; bsrc = b1; khl = 3; kwl = 3; }
  else if (q == 1) { wsrc = w2; bsrc = b2; khl = 2; kwl = 3; }
  else if (q == 2) { wsrc = w3; bsrc = b3; khl = 3; kwl = 2; }
  else             { wsrc = w4; bsrc = b4; khl = 2; kwl = 2; }
  if (t == 0) bias[row] = bsrc[co];
  ushort_t* dst = wt + (size_t)row * 4608;
  for (int tap = 0; tap < 9; ++tap) {
    const int dh = tap / 3, dw = tap % 3;
    const bool valid = (dh < khl) && (dw < kwl);
#pragma unroll
    for (int cc = 0; cc < 2; ++cc) {
      const int ci = cc * 256 + t;
      ushort_t v = 0;
      if (valid) v = f2bf(wsrc[(((size_t)co * 512 + ci) * khl + dh) * kwl + dw]);
      dst[tap * 512 + ci] = v;
    }
  }
}

// -------------------------------------------------------------- zero_stats --
__global__ void zero_stats(float* __restrict__ stats) {
  stats[threadIdx.x] = 0.f;   // 512 threads
}

// ------------------------------------------------------------------ gemm ---
// Block 128 m (4h x 32w) x 128 n; 4 waves in 2x2 grid, 4x4 frags each.
// K split into 8 chunks of 64 ci. Per chunk: stage X footprint (204 sites x
// 128 B) once; per tap: stage W tile (128 rows x 128 B) with one-tap-ahead
// register preload; 2 k-steps x 16 MFMA per tap.
__global__ __launch_bounds__(256, 3) void gemm_kernel(
    const ushort_t* __restrict__ xt, const ushort_t* __restrict__ wt,
    const float* __restrict__ bias, float* __restrict__ out,
    float* __restrict__ stats) {
  __shared__ char ldsX[NSITES * XSTR];   // 27,744 B
  __shared__ char ldsW[128 * XSTR];      // 17,408 B
  const int tid = threadIdx.x;
  const int bx = blockIdx.x;
  const int bn = bx & 7, bm = bx >> 3;
  const int n0 = bn << 7;
  const int n_img = bm >> 3;
  const int h0p = (bm & 7) << 2;        // first padded x_t row of footprint
  const int wv = tid >> 6, lane = tid & 63;
  const int ri = lane & 15, kg = lane >> 4;
  const int wm = (wv & 1) << 6, wn = (wv >> 1) << 6;

  // X footprint: 6 consecutive padded rows x 34 cols = contiguous 204 KB.
  const char* xg = (const char*)(xt + (size_t)(n_img * 34 + h0p) * (34 * 512));
  // X staging thread constants (idx = p*256+tid; 1632 16B-chunks total).
  // W staging: thread -> rows {i*32 + row8}, 16B chunk c8.
  const int row8 = tid >> 3, c8 = tid & 7;
  const char* wg[4];
#pragma unroll
  for (int i = 0; i < 4; ++i)
    wg[i] = (const char*)wt + (size_t)(n0 + i * 32 + row8) * 9216 + (c8 << 4);
  char* lw = ldsW + row8 * XSTR + (c8 << 4);

  // fragment LDS byte offsets
  int aadr[4], xadr[4];
#pragma unroll
  for (int f = 0; f < 4; ++f)
    aadr[f] = (wn + (f << 4) + ri) * XSTR + (kg << 4);
#pragma unroll
  for (int fj = 0; fj < 4; ++fj)
    xadr[fj] = ((((wm >> 5) + (fj >> 1)) * 34) + ((fj & 1) << 4) + ri) * XSTR +
               (kg << 4);

  floatx4 acc[4][4] = {};
  u32x4 wr[4];
#pragma unroll
  for (int i = 0; i < 4; ++i) wr[i] = *(const u32x4*)(wg[i]);  // chunk0 tap0

  for (int chunk = 0; chunk < 8; ++chunk) {
    const int cb = chunk << 7;
    // X chunk loads into regs (overlap previous taps' MFMA + the barrier)
    u32x4 xr[7];
#pragma unroll
    for (int p = 0; p < 7; ++p) {
      const int idx = p * 256 + tid;
      if (idx < 1632)
        xr[p] = *(const u32x4*)(xg + (idx >> 3) * 1024 + cb + ((idx & 7) << 4));
    }
    __syncthreads();                    // prev chunk's X/W LDS reads done
#pragma unroll
    for (int p = 0; p < 7; ++p) {
      const int idx = p * 256 + tid;
      if (idx < 1632)
        *(u32x4*)(ldsX + (idx >> 3) * XSTR + ((idx & 7) << 4)) = xr[p];
    }
#pragma unroll
    for (int i = 0; i < 4; ++i) *(u32x4*)(lw + i * 32 * XSTR) = wr[i];
    __syncthreads();
#pragma unroll
    for (int tap = 0; tap < 9; ++tap) {
      // preload next W tile into regs (overlaps this tap's MFMAs)
      u32x4 nr[4];
      const bool more = (tap < 8) || (chunk < 7);
      if (more) {
        const int noff = (tap < 8) ? ((tap + 1) << 10) + cb : (cb + 128);
#pragma unroll
        for (int i = 0; i < 4; ++i) nr[i] = *(const u32x4*)(wg[i] + noff);
      }
      const int tapo = ((tap / 3) * 34 + (tap % 3)) * XSTR;
#pragma unroll
      for (int ks = 0; ks < 2; ++ks) {
        short8 a4[4], b4[4];
#pragma unroll
        for (int f = 0; f < 4; ++f)
          a4[f] = *(const short8*)(ldsW + aadr[f] + (ks << 6));
#pragma unroll
        for (int fj = 0; fj < 4; ++fj)
          b4[fj] = *(const short8*)(ldsX + xadr[fj] + tapo + (ks << 6));
#pragma unroll
        for (int fi = 0; fi < 4; ++fi)
#pragma unroll
          for (int fj = 0; fj < 4; ++fj)
            acc[fi][fj] = __builtin_amdgcn_mfma_f32_16x16x32_bf16(
                a4[fi], b4[fj], acc[fi][fj], 0, 0, 0);
      }
      if (tap < 8) {
        __syncthreads();                // W reads done
#pragma unroll
        for (int i = 0; i < 4; ++i) *(u32x4*)(lw + i * 32 * XSTR) = nr[i];
        __syncthreads();                // W writes visible
      } else if (more) {
#pragma unroll
        for (int i = 0; i < 4; ++i) wr[i] = nr[i];
      }
    }
  }

  // ---- epilogue: +bias, dense 2x2 pixel-shuffle writes, fused BN stats ----
  // D layout: col=lane&15 (m), row=quad*4+reg (n). Interleaved W rows mean
  // reg == q (quadrant): co = (n0+wn+fi*16)/4 + quad.
  const int quad = kg, colL = ri;
#pragma unroll
  for (int fi = 0; fi < 4; ++fi) {
    const int co = ((n0 + wn + (fi << 4)) >> 2) + quad;
    const floatx4 bv = *(const floatx4*)(bias + n0 + wn + (fi << 4) + (quad << 2));
    float s = 0.f, s2 = 0.f;
    float* obase = out + ((size_t)(n_img * 256 + co) << 12);
#pragma unroll
    for (int fj = 0; fj < 4; ++fj) {
      const int mb = wm + (fj << 4) + colL;       // m within block
      const int hl = mb >> 5, w = mb & 31;
      const int h = h0p + hl;                     // global h (0..31)
      float v0 = acc[fi][fj][0] + bv[0];
      float v1 = acc[fi][fj][1] + bv[1];
      float v2 = acc[fi][fj][2] + bv[2];
      float v3 = acc[fi][fj][3] + bv[3];
      s += (v0 + v1) + (v2 + v3);
      s2 += v0 * v0 + v1 * v1 + v2 * v2 + v3 * v3;
      float* p = obase + (h << 7) + (w << 1);     // row 2h, col 2w
      floatx2 e = {v0, v2};
      floatx2 o = {v1, v3};
      *(floatx2*)p = e;
      *(floatx2*)(p + 64) = o;
    }
#pragma unroll
    for (int off = 1; off < 16; off <<= 1) {
      s += __shfl_xor(s, off);
      s2 += __shfl_xor(s2, off);
    }
    if (colL == 0) {
      atomicAdd(&stats[co], s);
      atomicAdd(&stats[256 + co], s2);
    }
  }
}

// -------------------------------------------------------------- bn_apply ---
__global__ __launch_bounds__(256) void bn_apply(
    float* __restrict__ y, const float* __restrict__ stats,
    const float* __restrict__ gamma, const float* __restrict__ beta) {
  const int b = blockIdx.x;
  const int co = b & 255;
  const int t = threadIdx.x;
  const float mean = stats[co] * (1.f / 65536.f);
  const float var = stats[256 + co] * (1.f / 65536.f) - mean * mean;
  const float rstd = rsqrtf(var + 1e-5f);
  const float scale = rstd * gamma[co];
  const float shift = beta[co] - mean * scale;
  float* p = y + (size_t)b * 4096;
#pragma unroll
  for (int it = 0; it < 4; ++it) {
    floatx4* q = (floatx4*)(p + (it * 256 + t) * 4);
    floatx4 v = *q;
#pragma unroll
    for (int e = 0; e < 4; ++e) v[e] = fmaxf(v[e] * scale + shift, 0.f);
    *q = v;
  }
}

// ---------------------------------------------------------------- launch ---
extern "C" void kernel_launch(void* const* d_in, const int* in_sizes, int n_in,
                              void* d_out, int out_size, void* d_ws,
                              size_t ws_size, hipStream_t stream) {
  const float* x  = (const float*)d_in[0];
  const float* w1 = (const float*)d_in[1];
  const float* b1 = (const float*)d_in[2];
  const float* w2 = (const float*)d_in[3];
  const float* b2 = (const float*)d_in[4];
  const float* w3 = (const float*)d_in[5];
  const float* b3 = (const float*)d_in[6];
  const float* w4 = (const float*)d_in[7];
  const float* b4 = (const float*)d_in[8];
  const float* gamma = (const float*)d_in[9];
  const float* beta  = (const float*)d_in[10];
  float* out = (float*)d_out;

  char* ws = (char*)d_ws;
  ushort_t* xt   = (ushort_t*)(ws + XT_OFF);
  ushort_t* wt   = (ushort_t*)(ws + WT_OFF);
  float*    bias = (float*)(ws + BIAS_OFF);
  float*    st   = (float*)(ws + STATS_OFF);

  zero_stats<<<1, 512, 0, stream>>>(st);
  prep_x<<<16 * 34, 256, 0, stream>>>(x, xt);
  prep_w<<<1024, 256, 0, stream>>>(w1, w2, w3, w4, b1, b2, b3, b4, wt, bias);
  gemm_kernel<<<1024, 256, 0, stream>>>(xt, wt, bias, out, st);
  bn_apply<<<4096, 256, 0, stream>>>(out, st, gamma, beta);
}

// Round 7
// 270.598 us; speedup vs baseline: 1.9920x; 1.4059x over previous
//
#include <hip/hip_runtime.h>
#include <hip/hip_bf16.h>

// FastUpConvolution on MI355X — round 7: ASYNC16 staging + XOR-swizzled LDS
// + double-buffered W (one barrier per tap).
// One implicit GEMM C[1024][16384] = W[1024][4608] * X[16384][4608]^T over
// NHWC-padded x (zero-padded taps), bf16 MFMA, f32 I/O.
//
// R6 post-mortem: stall-bound (MfmaUtil 24.5, VALU 9.5, HBM 18%, conflicts 0)
// — 160 barrier segments/block each with a reg-round-trip staging chain.
// R7 applies the m93->m97 proven lever (global_load_lds width=16, no VALU
// staging) to both operands; LDS is unpadded+XOR-swizzled (slot = c ^ (row&7))
// so the DMA's contiguous-dest constraint and bank-conflict-free frag reads
// coexist; W double-buffer halves barriers to 80/block and overlaps the
// W(t+1) fetch with tap t's MFMAs.
//
// ws layout:
//   x_t   : bf16 [16][34][34][512]  @ 0          (18,939,904 B)
//   W_t   : bf16 [1024 rows][9*512] @ 18,939,904 ( 9,437,184 B)  row=co*4+q
//   bias  : f32  [1024]             @ 28,377,088 (     4,096 B)  row=co*4+q
//   stats : f32  [512] sum|sumsq    @ 28,381,184 (     2,048 B)

typedef unsigned short ushort_t;
typedef __attribute__((ext_vector_type(8))) short short8;
typedef __attribute__((ext_vector_type(4))) float floatx4;
typedef __attribute__((ext_vector_type(2))) float floatx2;
typedef __attribute__((ext_vector_type(4))) unsigned short u16x4;
typedef __attribute__((ext_vector_type(8))) unsigned short u16x8;
typedef __attribute__((ext_vector_type(4))) unsigned int u32x4;

#define XT_OFF    0u
#define WT_OFF    18939904u
#define BIAS_OFF  28377088u
#define STATS_OFF 28381184u

#define NSITES 204            // 6 rows x 34 cols X footprint, 128 B per site

#define ASYNC16(g, l) __builtin_amdgcn_global_load_lds( \
    (const __attribute__((address_space(1))) void*)(g), \
    (__attribute__((address_space(3))) void*)(l), 16, 0, 0)

__device__ __forceinline__ ushort_t f2bf(float f) {
  unsigned int u = __builtin_bit_cast(unsigned int, f);
  u += 0x7fffu + ((u >> 16) & 1u);   // RNE (values finite here)
  return (ushort_t)(u >> 16);
}

// ---------------------------------------------------------------- prep_x ---
// x[16][512][32][32] (f32) -> x_t[16][34][34][512] bf16, zero-padded NHWC.
__global__ __launch_bounds__(256) void prep_x(const float* __restrict__ x,
                                              ushort_t* __restrict__ xt) {
  const int b = blockIdx.x;
  const int n = b / 34, hp = b % 34;
  const int t = threadIdx.x;
  ushort_t* dst = xt + (size_t)(n * 34 + hp) * (34 * 512);
  if (hp == 0 || hp == 33) {
    u32x4 z = {0u, 0u, 0u, 0u};
    for (int i = t; i < 2176; i += 256) ((u32x4*)dst)[i] = z;
    return;
  }
  const int h = hp - 1;
  {
    u32x4 z = {0u, 0u, 0u, 0u};
    if (t < 64) ((u32x4*)dst)[t] = z;
    else if (t < 128) ((u32x4*)(dst + 33 * 512))[t - 64] = z;
  }
  __shared__ ushort_t lds[128 * 36];
  const size_t base = (size_t)n * 524288 + (size_t)h * 32;
  for (int ci0 = 0; ci0 < 512; ci0 += 128) {
    __syncthreads();
    {
      const int cil = t >> 3;
      const int w4 = (t & 7) << 2;
#pragma unroll
      for (int cc = 0; cc < 4; ++cc) {
        const int ci = cil + cc * 32;
        floatx4 v = *(const floatx4*)(x + base + (size_t)(ci0 + ci) * 1024 + w4);
        u16x4 hv;
#pragma unroll
        for (int j = 0; j < 4; ++j) hv[j] = f2bf(v[j]);
        *(u16x4*)&lds[ci * 36 + w4] = hv;
      }
    }
    __syncthreads();
    {
      const int w = t & 31;
      const int j8 = t >> 5;
#pragma unroll
      for (int cc2 = 0; cc2 < 2; ++cc2) {
        const int cil = cc2 * 64 + j8 * 8;
        u16x8 v;
#pragma unroll
        for (int j = 0; j < 8; ++j) v[j] = lds[(cil + j) * 36 + w];
        *(u16x8*)(dst + (w + 1) * 512 + ci0 + cil) = v;
      }
    }
  }
}

// ---------------------------------------------------------------- prep_w ---
// W_t[row=co*4+q][tap][ci] bf16; q0=3x3 q1=2x3 q2=3x2 q3=2x2; bias[row].
__global__ __launch_bounds__(256) void prep_w(
    const float* __restrict__ w1, const float* __restrict__ w2,
    const float* __restrict__ w3, const float* __restrict__ w4,
    const float* __restrict__ b1, const float* __restrict__ b2,
    const float* __restrict__ b3, const float* __restrict__ b4,
    ushort_t* __restrict__ wt, float* __restrict__ bias) {
  const int nout = blockIdx.x;
  const int q = nout >> 8, co = nout & 255;
  const int row = co * 4 + q;
  const int t = threadIdx.x;
  const float* wsrc; const float* bsrc; int khl, kwl;
  if (q == 0)      { wsrc = w1; bsrc = b1; khl = 3; kwl = 3; }
  else if (q == 1) { wsrc = w2; bsrc = b2; khl = 2; kwl = 3; }
  else if (q == 2) { wsrc = w3; bsrc = b3; khl = 3; kwl = 2; }
  else             { wsrc = w4; bsrc = b4; khl = 2; kwl = 2; }
  if (t == 0) bias[row] = bsrc[co];
  ushort_t* dst = wt + (size_t)row * 4608;
  for (int tap = 0; tap < 9; ++tap) {
    const int dh = tap / 3, dw = tap % 3;
    const bool valid = (dh < khl) && (dw < kwl);
#pragma unroll
    for (int cc = 0; cc < 2; ++cc) {
      const int ci = cc * 256 + t;
      ushort_t v = 0;
      if (valid) v = f2bf(wsrc[(((size_t)co * 512 + ci) * khl + dh) * kwl + dw]);
      dst[tap * 512 + ci] = v;
    }
  }
}

// -------------------------------------------------------------- zero_stats --
__global__ void zero_stats(float* __restrict__ stats) {
  stats[threadIdx.x] = 0.f;   // 512 threads
}

// ------------------------------------------------------------------ gemm ---
// Block 128 m (4h x 32w) x 128 n; 4 waves 2x2, 4x4 frags of 16x16x32 bf16.
// K = 8 chunks x 64 ci. Per chunk: ASYNC16-stage X footprint (204 sites x
// 128 B) once + W(tap0); per tap: ASYNC16-stage W(tap+1) into the other
// buffer, 2 k-steps x 16 MFMA, one barrier. LDS unpadded, XOR-swizzled:
// 16B chunk c of row r lives at slot c^(r&7) -> DMA dest contiguous AND
// frag reads conflict-free.
__global__ __launch_bounds__(256) void gemm_kernel(
    const ushort_t* __restrict__ xt, const ushort_t* __restrict__ wt,
    const float* __restrict__ bias, float* __restrict__ out,
    float* __restrict__ stats) {
  __shared__ char ldsX[NSITES * 128];    // 26,112 B
  __shared__ char ldsW[2][128 * 128];    // 2 x 16,384 B
  const int tid = threadIdx.x;
  const int bx = blockIdx.x;
  const int bn = bx & 7, bm = bx >> 3;
  const int n0 = bn << 7;
  const int n_img = bm >> 3;
  const int h0p = (bm & 7) << 2;        // first padded x_t row of footprint
  const int wv = tid >> 6, lane = tid & 63;
  const int ri = lane & 15, kg = lane >> 4;
  const int wm = (wv & 1) << 6, wn = (wv >> 1) << 6;

  // ---- staging pointer precompute (XOR swizzle at issue) ----
  // X: idx = p*256+tid over 1632 = 204 sites x 8 slots; slot holds chunk
  // c = slot ^ (site&7). LDS dest = ldsX + idx*16 (contiguous per wave).
  const char* xgp[7];
  char* xlp[7];
  {
    const char* xg = (const char*)(xt + (size_t)(n_img * 34 + h0p) * (34 * 512));
#pragma unroll
    for (int p = 0; p < 7; ++p) {
      const int idx = p * 256 + tid;
      const int site = idx >> 3, slot = idx & 7;
      const int c = slot ^ (site & 7);
      xgp[p] = xg + site * 1024 + (c << 4);
      xlp[p] = ldsX + idx * 16;
    }
  }
  // W: idx = p*256+tid over 1024 = 128 rows x 8 slots.
  const char* wgp[4];
  char* wlp0[4];
  char* wlp1[4];
#pragma unroll
  for (int p = 0; p < 4; ++p) {
    const int idx = p * 256 + tid;
    const int row = idx >> 3, slot = idx & 7;
    const int c = slot ^ (row & 7);
    wgp[p] = (const char*)wt + (size_t)(n0 + row) * 9216 + (c << 4);
    wlp0[p] = ldsW[0] + idx * 16;
    wlp1[p] = ldsW[1] + idx * 16;
  }

  floatx4 acc[4][4] = {};

  // fragment row/site indices
  int arow[4], bsite[4];
#pragma unroll
  for (int f = 0; f < 4; ++f) arow[f] = wn + (f << 4) + ri;
#pragma unroll
  for (int fj = 0; fj < 4; ++fj)
    bsite[fj] = ((wm >> 5) + (fj >> 1)) * 34 + ((fj & 1) << 4) + ri;

  for (int chunk = 0; chunk < 8; ++chunk) {
    const int cb = chunk << 7;
    // stage X footprint chunk + W(tap0) -> buf0 (prev readers done at the
    // barrier that ended the previous chunk's last tap)
#pragma unroll
    for (int p = 0; p < 6; ++p) ASYNC16(xgp[p] + cb, xlp[p]);
    if (tid < 96) ASYNC16(xgp[6] + cb, xlp[6]);   // tail: 1632 = 6*256+96
#pragma unroll
    for (int p = 0; p < 4; ++p) ASYNC16(wgp[p] + cb, wlp0[p]);
    __syncthreads();                     // drain vmcnt -> X + W0 visible
#pragma unroll
    for (int tap = 0; tap < 9; ++tap) {
      // prefetch W(tap+1) into the other buffer (freed by last barrier)
      if (tap < 8) {
        const int noff = ((tap + 1) << 10) + cb;
        if (tap & 1) {
#pragma unroll
          for (int p = 0; p < 4; ++p) ASYNC16(wgp[p] + noff, wlp0[p]);
        } else {
#pragma unroll
          for (int p = 0; p < 4; ++p) ASYNC16(wgp[p] + noff, wlp1[p]);
        }
      }
      const char* wb = ldsW[tap & 1];
      const int tapo = ((tap / 3) * 34 + (tap % 3)) * 128;
#pragma unroll
      for (int ks = 0; ks < 2; ++ks) {
        const int c = (ks << 2) + kg;    // 16B chunk index within row
        short8 a4[4], b4[4];
#pragma unroll
        for (int f = 0; f < 4; ++f)
          a4[f] = *(const short8*)(wb + arow[f] * 128 +
                                   ((c ^ (arow[f] & 7)) << 4));
#pragma unroll
        for (int fj = 0; fj < 4; ++fj) {
          const int sadr = bsite[fj] * 128 + tapo;
          // note: tapo shifts the site index; swizzle uses the SHIFTED row
          const int srow = bsite[fj] + (tap / 3) * 34 + (tap % 3);
          b4[fj] = *(const short8*)(ldsX + sadr + ((c ^ (srow & 7)) << 4));
        }
#pragma unroll
        for (int fi = 0; fi < 4; ++fi)
#pragma unroll
          for (int fj = 0; fj < 4; ++fj)
            acc[fi][fj] = __builtin_amdgcn_mfma_f32_16x16x32_bf16(
                a4[fi], b4[fj], acc[fi][fj], 0, 0, 0);
      }
      __syncthreads();   // readers of wb & (last tap) X done; W(t+1) drained
    }
  }

  // ---- epilogue: +bias, dense 2x2 pixel-shuffle writes, fused BN stats ----
  // D layout: col=lane&15 (m), row=quad*4+reg (n). Interleaved W rows mean
  // reg == q (quadrant): co = (n0+wn+fi*16)/4 + quad.
  const int quad = kg, colL = ri;
#pragma unroll
  for (int fi = 0; fi < 4; ++fi) {
    const int co = ((n0 + wn + (fi << 4)) >> 2) + quad;
    const floatx4 bv = *(const floatx4*)(bias + n0 + wn + (fi << 4) + (quad << 2));
    float s = 0.f, s2 = 0.f;
    float* obase = out + ((size_t)(n_img * 256 + co) << 12);
#pragma unroll
    for (int fj = 0; fj < 4; ++fj) {
      const int mb = wm + (fj << 4) + colL;       // m within block
      const int hl = mb >> 5, w = mb & 31;
      const int h = h0p + hl;                     // global h (0..31)
      float v0 = acc[fi][fj][0] + bv[0];
      float v1 = acc[fi][fj][1] + bv[1];
      float v2 = acc[fi][fj][2] + bv[2];
      float v3 = acc[fi][fj][3] + bv[3];
      s += (v0 + v1) + (v2 + v3);
      s2 += v0 * v0 + v1 * v1 + v2 * v2 + v3 * v3;
      float* p = obase + (h << 7) + (w << 1);     // row 2h, col 2w
      floatx2 e = {v0, v2};
      floatx2 o = {v1, v3};
      *(floatx2*)p = e;
      *(floatx2*)(p + 64) = o;
    }
#pragma unroll
    for (int off = 1; off < 16; off <<= 1) {
      s += __shfl_xor(s, off);
      s2 += __shfl_xor(s2, off);
    }
    if (colL == 0) {
      atomicAdd(&stats[co], s);
      atomicAdd(&stats[256 + co], s2);
    }
  }
}

// -------------------------------------------------------------- bn_apply ---
__global__ __launch_bounds__(256) void bn_apply(
    float* __restrict__ y, const float* __restrict__ stats,
    const float* __restrict__ gamma, const float* __restrict__ beta) {
  const int b = blockIdx.x;
  const int co = b & 255;
  const int t = threadIdx.x;
  const float mean = stats[co] * (1.f / 65536.f);
  const float var = stats[256 + co] * (1.f / 65536.f) - mean * mean;
  const float rstd = rsqrtf(var + 1e-5f);
  const float scale = rstd * gamma[co];
  const float shift = beta[co] - mean * scale;
  float* p = y + (size_t)b * 4096;
#pragma unroll
  for (int it = 0; it < 4; ++it) {
    floatx4* q = (floatx4*)(p + (it * 256 + t) * 4);
    floatx4 v = *q;
#pragma unroll
    for (int e = 0; e < 4; ++e) v[e] = fmaxf(v[e] * scale + shift, 0.f);
    *q = v;
  }
}

// ---------------------------------------------------------------- launch ---
extern "C" void kernel_launch(void* const* d_in, const int* in_sizes, int n_in,
                              void* d_out, int out_size, void* d_ws,
                              size_t ws_size, hipStream_t stream) {
  const float* x  = (const float*)d_in[0];
  const float* w1 = (const float*)d_in[1];
  const float* b1 = (const float*)d_in[2];
  const float* w2 = (const float*)d_in[3];
  const float* b2 = (const float*)d_in[4];
  const float* w3 = (const float*)d_in[5];
  const float* b3 = (const float*)d_in[6];
  const float* w4 = (const float*)d_in[7];
  const float* b4 = (const float*)d_in[8];
  const float* gamma = (const float*)d_in[9];
  const float* beta  = (const float*)d_in[10];
  float* out = (float*)d_out;

  char* ws = (char*)d_ws;
  ushort_t* xt   = (ushort_t*)(ws + XT_OFF);
  ushort_t* wt   = (ushort_t*)(ws + WT_OFF);
  float*    bias = (float*)(ws + BIAS_OFF);
  float*    st   = (float*)(ws + STATS_OFF);

  zero_stats<<<1, 512, 0, stream>>>(st);
  prep_x<<<16 * 34, 256, 0, stream>>>(x, xt);
  prep_w<<<1024, 256, 0, stream>>>(w1, w2, w3, w4, b1, b2, b3, b4, wt, bias);
  gemm_kernel<<<1024, 256, 0, stream>>>(xt, wt, bias, out, st);
  bn_apply<<<4096, 256, 0, stream>>>(out, st, gamma, beta);
}